// Round 1
// baseline (637.367 us; speedup 1.0000x reference)
//
#include <hip/hip_runtime.h>
#include <hip/hip_bf16.h>
#include <math.h>

typedef __bf16 bf16;
typedef __bf16 v8bf __attribute__((ext_vector_type(8)));
typedef float  v4f  __attribute__((ext_vector_type(4)));

#define B_   128
#define KK_  49
#define D_   512
#define E_   256
#define V_   10000
#define T_   20
#define NG_  2048   // 4*D
#define XK_  768    // E+D
#define VPAD 10112  // 79*128 (Wp rows padded)
#define NP_  128    // padded small-N

// ---------------------------------------------------------------------------
// Prep: fp32->bf16 conversions, padding, gather of LSTM input rows
// ---------------------------------------------------------------------------
__global__ void prep_kernel(
    const float* __restrict__ spatial, const float* __restrict__ gfeat,
    const int* __restrict__ caps, const float* __restrict__ emb,
    const float* __restrict__ W_init_h, const float* __restrict__ W_init_m,
    const float* __restrict__ W_ih, const float* __restrict__ b_ih,
    const float* __restrict__ W_hh, const float* __restrict__ b_hh,
    const float* __restrict__ Wv, const float* __restrict__ bv,
    const float* __restrict__ Wg, const float* __restrict__ bg,
    const float* __restrict__ Wp,
    bf16* __restrict__ Wp_b, bf16* __restrict__ Whh_b, bf16* __restrict__ Wih_b,
    bf16* __restrict__ Xin_b, bf16* __restrict__ Sp_b,
    bf16* __restrict__ Wv_b, bf16* __restrict__ Wg_b,
    bf16* __restrict__ Winh_b, bf16* __restrict__ Winm_b, bf16* __restrict__ Gf_b,
    float* __restrict__ bias_comb, float* __restrict__ bv_pad, float* __restrict__ bg_pad)
{
    const int stride = gridDim.x * blockDim.x;
    const int tid0 = blockIdx.x * blockDim.x + threadIdx.x;

    // Wp -> bf16, padded to VPAD rows
    for (int i = tid0; i < VPAD * D_; i += stride) {
        int row = i >> 9;
        Wp_b[i] = (row < V_) ? (bf16)Wp[i] : (bf16)0.f;
    }
    // W_hh -> bf16
    for (int i = tid0; i < NG_ * D_; i += stride) Whh_b[i] = (bf16)W_hh[i];
    // W_ih -> bf16
    for (int i = tid0; i < NG_ * XK_; i += stride) Wih_b[i] = (bf16)W_ih[i];
    // Xin rows r = t*128+b : [emb[captions[b,t]], global_feats[b]]
    for (int i = tid0; i < T_ * B_ * XK_; i += stride) {
        int r = i / XK_, c = i - r * XK_;
        int t = r >> 7, b = r & 127;
        float v;
        if (c < E_) v = emb[(long)caps[b * T_ + t] * E_ + c];
        else        v = gfeat[(long)b * D_ + (c - E_)];
        Xin_b[i] = (bf16)v;
    }
    // spatial -> bf16 (flattened [B*K, D])
    for (int i = tid0; i < B_ * KK_ * D_; i += stride) Sp_b[i] = (bf16)spatial[i];
    // Wv padded to 128 rows
    for (int i = tid0; i < NP_ * D_; i += stride) {
        int row = i >> 9;
        Wv_b[i] = (row < KK_) ? (bf16)Wv[i] : (bf16)0.f;
    }
    // Wg padded
    for (int i = tid0; i < NP_ * D_; i += stride) {
        int row = i >> 9;
        Wg_b[i] = (row < KK_) ? (bf16)Wg[i] : (bf16)0.f;
    }
    // W_init_h / W_init_m
    for (int i = tid0; i < D_ * D_; i += stride) Winh_b[i] = (bf16)W_init_h[i];
    for (int i = tid0; i < D_ * D_; i += stride) Winm_b[i] = (bf16)W_init_m[i];
    // global_feats -> bf16
    for (int i = tid0; i < B_ * D_; i += stride) Gf_b[i] = (bf16)gfeat[i];
    // combined gate bias
    for (int i = tid0; i < NG_; i += stride) bias_comb[i] = b_ih[i] + b_hh[i];
    // padded small biases
    for (int i = tid0; i < NP_; i += stride) bv_pad[i] = (i < KK_) ? bv[i] : 0.f;
    for (int i = tid0; i < NP_; i += stride) bg_pad[i] = (i < KK_) ? bg[i] : 0.f;
}

// ---------------------------------------------------------------------------
// Generic bf16 MFMA GEMM: C[M,N] = A[M,K] @ Bm[N,K]^T + bias[n]
// 128x128 tile, 4 waves, each wave 64x64 (4x4 of 16x16x32 MFMA).
// OUTMODE: 0 = f32 store, 1 = bf16 store, 2 = logits (f32, clip n<n_real,
//          zero rows where t >= lengths[b], row = b*T + t, stride out_stride)
// ---------------------------------------------------------------------------
template <int OUTMODE>
__global__ __launch_bounds__(256) void gemm_bt(
    const bf16* __restrict__ A, const bf16* __restrict__ Bm,
    const float* __restrict__ bias, void* __restrict__ Cout,
    int M, int N, int K, int out_stride, int n_real, const int* __restrict__ lengths)
{
    __shared__ bf16 As[128 * 32];
    __shared__ bf16 Bs[128 * 32];
    const int m0 = blockIdx.y * 128, n0 = blockIdx.x * 128;
    const int tid = threadIdx.x;
    const int w = tid >> 6, l = tid & 63;
    const int wm = (w >> 1) * 64, wn = (w & 1) * 64;
    const int lr = l & 15, lq = l >> 4;

    v4f acc[4][4] = {};

    for (int k0 = 0; k0 < K; k0 += 32) {
        __syncthreads();
        #pragma unroll
        for (int c = 0; c < 2; c++) {
            int u = c * 256 + tid;
            int row = u >> 2, kc = (u & 3) * 8;
            *(int4*)&As[u * 8] = *(const int4*)&A[(long)(m0 + row) * K + k0 + kc];
            *(int4*)&Bs[u * 8] = *(const int4*)&Bm[(long)(n0 + row) * K + k0 + kc];
        }
        __syncthreads();
        v8bf af[4], bfv[4];
        #pragma unroll
        for (int s = 0; s < 4; s++) {
            af[s]  = *(const v8bf*)&As[(wm + s * 16 + lr) * 32 + lq * 8];
            bfv[s] = *(const v8bf*)&Bs[(wn + s * 16 + lr) * 32 + lq * 8];
        }
        #pragma unroll
        for (int i = 0; i < 4; i++)
            #pragma unroll
            for (int j = 0; j < 4; j++)
                acc[i][j] = __builtin_amdgcn_mfma_f32_16x16x32_bf16(af[i], bfv[j], acc[i][j], 0, 0, 0);
    }

    #pragma unroll
    for (int i = 0; i < 4; i++)
        #pragma unroll
        for (int j = 0; j < 4; j++)
            #pragma unroll
            for (int r = 0; r < 4; r++) {
                int m = m0 + wm + i * 16 + lq * 4 + r;
                int n = n0 + wn + j * 16 + lr;
                float v = acc[i][j][r];
                if (OUTMODE == 2) {
                    if (n < n_real) {
                        int t = m % T_, b = m / T_;
                        float o = (t < lengths[b]) ? (v + bias[n]) : 0.f;
                        ((float*)Cout)[(long)m * out_stride + n] = o;
                    }
                } else if (OUTMODE == 1) {
                    ((bf16*)Cout)[(long)m * out_stride + n] = (bf16)(v + bias[n]);
                } else {
                    ((float*)Cout)[(long)m * out_stride + n] = v + bias[n];
                }
            }
}

// ---------------------------------------------------------------------------
// Per-step fused kernel: gates = Xpre[t] + h_{t-1} @ W_hh^T, LSTM cell update.
// grid (8 b-tiles, 8 j-tiles), 256 thr = 4 waves; wave w owns gate w.
// Each wave: 16(b) x 64(j) output via 4 MFMA subtiles, K=512.
// ---------------------------------------------------------------------------
__global__ __launch_bounds__(256) void step_kernel(
    const bf16* __restrict__ Hprev, bf16* __restrict__ Hnext,
    const bf16* __restrict__ Whh_b, const float* __restrict__ Xpre_t,
    float* __restrict__ mbuf, const int* __restrict__ lengths, int t)
{
    const int b0 = blockIdx.x * 16;
    const int j0 = blockIdx.y * 64;
    const int tid = threadIdx.x;
    const int w = tid >> 6, l = tid & 63;   // w = gate index (i,f,g,o)
    const int lr = l & 15, lq = l >> 4;
    __shared__ float g4[4][16][64];

    v4f acc[4] = {};
    const bf16* Arow = Hprev + (long)(b0 + lr) * D_;
    const bf16* Brow = Whh_b + (long)(w * D_ + j0) * D_;

    for (int kk = 0; kk < D_; kk += 32) {
        v8bf af = *(const v8bf*)&Arow[kk + lq * 8];
        #pragma unroll
        for (int s = 0; s < 4; s++) {
            v8bf bfv = *(const v8bf*)&Brow[(long)(s * 16 + lr) * D_ + kk + lq * 8];
            acc[s] = __builtin_amdgcn_mfma_f32_16x16x32_bf16(af, bfv, acc[s], 0, 0, 0);
        }
    }
    #pragma unroll
    for (int s = 0; s < 4; s++)
        #pragma unroll
        for (int r = 0; r < 4; r++)
            g4[w][lq * 4 + r][s * 16 + lr] = acc[s][r];
    __syncthreads();

    for (int p = tid; p < 16 * 64; p += 256) {
        int bi = p >> 6, j = p & 63;
        int bgl = b0 + bi, jg = j0 + j;
        const float* xp = Xpre_t + (long)bgl * NG_ + jg;
        float gi = g4[0][bi][j] + xp[0];
        float gf = g4[1][bi][j] + xp[D_];
        float gc = g4[2][bi][j] + xp[2 * D_];
        float go = g4[3][bi][j] + xp[3 * D_];
        gi = 1.f / (1.f + expf(-gi));
        gf = 1.f / (1.f + expf(-gf));
        gc = tanhf(gc);
        go = 1.f / (1.f + expf(-go));
        long idx = (long)bgl * D_ + jg;
        float m_old = mbuf[idx];
        float h_old = (float)Hprev[idx];
        bool active = t < lengths[bgl];
        float m_new = gf * m_old + gi * gc;
        float h_new = go * tanhf(m_new);
        mbuf[idx] = active ? m_new : m_old;
        Hnext[idx] = (bf16)(active ? h_new : h_old);
    }
}

// ---------------------------------------------------------------------------
// Attention + context, parallel over all (t,b). One wave per (t,b).
// z[k'] = sum_j wh[j]*tanh(Vproj[b,k',j] + g[j]) + bh; softmax; c = alpha@spatial
// ctx[b*T+t] = c + h_t   (bf16)
// ---------------------------------------------------------------------------
__global__ __launch_bounds__(64) void attn_kernel(
    const bf16* __restrict__ Hb16, const float* __restrict__ g_all,
    const float* __restrict__ Vproj, const float* __restrict__ wh,
    const float* __restrict__ bh_att, const float* __restrict__ spatial,
    bf16* __restrict__ ctx)
{
    const int r = blockIdx.x;          // t*128 + b
    const int t = r >> 7, b = r & 127;
    const int l = threadIdx.x;
    __shared__ float sg[64], sal[64], swh[64];

    if (l < KK_) { sg[l] = g_all[(long)r * NP_ + l]; swh[l] = wh[l]; }
    __syncthreads();

    float z = -1e30f;
    if (l < KK_) {
        const float* vp = Vproj + (long)(b * KK_ + l) * NP_;
        float a = 0.f;
        for (int j = 0; j < KK_; j++)
            a += swh[j] * tanhf(vp[j] + sg[j]);
        z = a + bh_att[0];
    }
    float mx = z;
    #pragma unroll
    for (int o = 32; o > 0; o >>= 1) mx = fmaxf(mx, __shfl_xor(mx, o));
    float e = (l < KK_) ? expf(z - mx) : 0.f;
    float sm = e;
    #pragma unroll
    for (int o = 32; o > 0; o >>= 1) sm += __shfl_xor(sm, o);
    sal[l] = e / sm;
    __syncthreads();

    const bf16* hrow = Hb16 + (long)(t + 1) * B_ * D_ + (long)b * D_;
    const float* sp = spatial + (long)b * KK_ * D_;
    bf16* crow = ctx + (long)(b * T_ + t) * D_;
    for (int d = l; d < D_; d += 64) {
        float c = 0.f;
        for (int k = 0; k < KK_; k++)
            c += sal[k] * sp[k * D_ + d];
        crow[d] = (bf16)(c + (float)hrow[d]);
    }
}

// ---------------------------------------------------------------------------
extern "C" void kernel_launch(void* const* d_in, const int* in_sizes, int n_in,
                              void* d_out, int out_size, void* d_ws, size_t ws_size,
                              hipStream_t stream)
{
    const float* spatial  = (const float*)d_in[0];
    const float* gfeat    = (const float*)d_in[1];
    const int*   caps     = (const int*)d_in[2];
    const int*   lengths  = (const int*)d_in[3];
    const float* emb      = (const float*)d_in[4];
    const float* W_init_h = (const float*)d_in[5];
    const float* b_init_h = (const float*)d_in[6];
    const float* W_init_m = (const float*)d_in[7];
    const float* b_init_m = (const float*)d_in[8];
    const float* W_ih     = (const float*)d_in[9];
    const float* b_ih     = (const float*)d_in[10];
    const float* W_hh     = (const float*)d_in[11];
    const float* b_hh     = (const float*)d_in[12];
    const float* Wv       = (const float*)d_in[13];
    const float* bv       = (const float*)d_in[14];
    const float* Wg       = (const float*)d_in[15];
    const float* bg       = (const float*)d_in[16];
    const float* wh       = (const float*)d_in[17];
    const float* bh_att   = (const float*)d_in[18];
    const float* Wp       = (const float*)d_in[19];
    const float* bp       = (const float*)d_in[20];
    float* out = (float*)d_out;

    char* ws = (char*)d_ws;
    size_t off = 0;
    auto alloc = [&](size_t bytes) -> void* {
        off = (off + 255) & ~(size_t)255;
        void* p = ws + off;
        off += bytes;
        return p;
    };

    bf16* Wp_b   = (bf16*)alloc((size_t)VPAD * D_ * 2);
    bf16* Whh_b  = (bf16*)alloc((size_t)NG_ * D_ * 2);
    bf16* Wih_b  = (bf16*)alloc((size_t)NG_ * XK_ * 2);
    bf16* Xin_b  = (bf16*)alloc((size_t)T_ * B_ * XK_ * 2);
    bf16* Sp_b   = (bf16*)alloc((size_t)B_ * KK_ * D_ * 2);
    bf16* Wv_b   = (bf16*)alloc((size_t)NP_ * D_ * 2);
    bf16* Wg_b   = (bf16*)alloc((size_t)NP_ * D_ * 2);
    bf16* Winh_b = (bf16*)alloc((size_t)D_ * D_ * 2);
    bf16* Winm_b = (bf16*)alloc((size_t)D_ * D_ * 2);
    bf16* Gf_b   = (bf16*)alloc((size_t)B_ * D_ * 2);
    float* bias_comb = (float*)alloc(NG_ * 4);
    float* bv_pad    = (float*)alloc(NP_ * 4);
    float* bg_pad    = (float*)alloc(NP_ * 4);
    bf16* Hb16   = (bf16*)alloc((size_t)(T_ + 1) * B_ * D_ * 2);
    float* mbuf  = (float*)alloc((size_t)B_ * D_ * 4);
    float* Xpre  = (float*)alloc((size_t)T_ * B_ * NG_ * 4);
    float* VprojW = (float*)alloc((size_t)B_ * KK_ * NP_ * 4);
    float* g_allW = (float*)alloc((size_t)T_ * B_ * NP_ * 4);
    bf16* ctx    = (bf16*)alloc((size_t)T_ * B_ * D_ * 2);

    // 1. prep / conversions
    prep_kernel<<<1024, 256, 0, stream>>>(
        spatial, gfeat, caps, emb, W_init_h, W_init_m, W_ih, b_ih, W_hh, b_hh,
        Wv, bv, Wg, bg, Wp,
        Wp_b, Whh_b, Wih_b, Xin_b, Sp_b, Wv_b, Wg_b, Winh_b, Winm_b, Gf_b,
        bias_comb, bv_pad, bg_pad);

    // 2. h0 (bf16 into Hb16[0]) and m0 (f32 into mbuf)
    gemm_bt<1><<<dim3(4, 1), 256, 0, stream>>>(Gf_b, Winh_b, b_init_h, Hb16,
                                               B_, D_, D_, D_, 0, nullptr);
    gemm_bt<0><<<dim3(4, 1), 256, 0, stream>>>(Gf_b, Winm_b, b_init_m, mbuf,
                                               B_, D_, D_, D_, 0, nullptr);

    // 3. V_proj = spatial @ Wv^T + bv  -> [B*K, 128] f32
    gemm_bt<0><<<dim3(1, (B_ * KK_) / 128), 256, 0, stream>>>(
        Sp_b, Wv_b, bv_pad, VprojW, B_ * KK_, NP_, D_, NP_, 0, nullptr);

    // 4. Xpre = Xin @ W_ih^T + (b_ih + b_hh)  -> [T*B, 2048] f32
    gemm_bt<0><<<dim3(NG_ / 128, (T_ * B_) / 128), 256, 0, stream>>>(
        Xin_b, Wih_b, bias_comb, Xpre, T_ * B_, NG_, XK_, NG_, 0, nullptr);

    // 5. sequential LSTM steps
    for (int t = 0; t < T_; t++) {
        step_kernel<<<dim3(8, 8), 256, 0, stream>>>(
            Hb16 + (size_t)t * B_ * D_, Hb16 + (size_t)(t + 1) * B_ * D_,
            Whh_b, Xpre + (size_t)t * B_ * NG_, mbuf, lengths, t);
    }

    // 6. g_all = H[1..T] @ Wg^T + bg  -> [T*B, 128] f32
    gemm_bt<0><<<dim3(1, (T_ * B_) / 128), 256, 0, stream>>>(
        Hb16 + (size_t)B_ * D_, Wg_b, bg_pad, g_allW, T_ * B_, NP_, D_, NP_, 0, nullptr);

    // 7. attention + ctx = c + h  (bf16, rows b*T+t)
    attn_kernel<<<T_ * B_, 64, 0, stream>>>(Hb16, g_allW, VprojW, wh, bh_att,
                                            spatial, ctx);

    // 8. logits = ctx @ Wp^T + bp, masked, -> d_out [B*T, V]
    gemm_bt<2><<<dim3(VPAD / 128, (T_ * B_) / 128), 256, 0, stream>>>(
        ctx, Wp_b, bp, out, T_ * B_, VPAD, D_, V_, V_, lengths);
}

// Round 2
// 490.291 us; speedup vs baseline: 1.3000x; 1.3000x over previous
//
#include <hip/hip_runtime.h>
#include <hip/hip_bf16.h>
#include <math.h>

typedef __bf16 bf16;
typedef __bf16 v8bf __attribute__((ext_vector_type(8)));
typedef __bf16 v4bfv __attribute__((ext_vector_type(4)));
typedef float  v4f  __attribute__((ext_vector_type(4)));

#define B_   128
#define KK_  49
#define D_   512
#define E_   256
#define V_   10000
#define T_   20
#define NG_  2048   // 4*D
#define XK_  768    // E+D
#define VPAD 10112  // 79*128 (Wp rows padded)
#define NP_  128    // padded small-N

#define GLOAD_LDS16(gp, lp) \
    __builtin_amdgcn_global_load_lds((const __attribute__((address_space(1))) void*)(gp), \
                                     (__attribute__((address_space(3))) void*)(lp), 16, 0, 0)

__device__ inline v4bfv cvt4(float4 v) {
    v4bfv o; o[0] = (bf16)v.x; o[1] = (bf16)v.y; o[2] = (bf16)v.z; o[3] = (bf16)v.w;
    return o;
}

// ---------------------------------------------------------------------------
// Prep: fp32->bf16 conversions (float4-vectorized), padding, gather of LSTM
// input rows.
// ---------------------------------------------------------------------------
__global__ void prep_kernel(
    const float* __restrict__ spatial, const float* __restrict__ gfeat,
    const int* __restrict__ caps, const float* __restrict__ emb,
    const float* __restrict__ W_init_h, const float* __restrict__ W_init_m,
    const float* __restrict__ W_ih, const float* __restrict__ b_ih,
    const float* __restrict__ W_hh, const float* __restrict__ b_hh,
    const float* __restrict__ Wv, const float* __restrict__ bv,
    const float* __restrict__ Wg, const float* __restrict__ bg,
    const float* __restrict__ Wp,
    bf16* __restrict__ Wp_b, bf16* __restrict__ Whh_b, bf16* __restrict__ Wih_b,
    bf16* __restrict__ Xin_b, bf16* __restrict__ Sp_b,
    bf16* __restrict__ Wv_b, bf16* __restrict__ Wg_b,
    bf16* __restrict__ Winh_b, bf16* __restrict__ Winm_b, bf16* __restrict__ Gf_b,
    float* __restrict__ bias_comb, float* __restrict__ bv_pad, float* __restrict__ bg_pad)
{
    const int stride = gridDim.x * blockDim.x;
    const int tid0 = blockIdx.x * blockDim.x + threadIdx.x;
    const float4 z4 = make_float4(0.f, 0.f, 0.f, 0.f);

    // Wp -> bf16, padded to VPAD rows
    for (int i4 = tid0; i4 < VPAD * D_ / 4; i4 += stride) {
        int row = i4 >> 7;
        float4 v = (row < V_) ? ((const float4*)Wp)[i4] : z4;
        ((v4bfv*)Wp_b)[i4] = cvt4(v);
    }
    // W_hh -> bf16
    for (int i4 = tid0; i4 < NG_ * D_ / 4; i4 += stride)
        ((v4bfv*)Whh_b)[i4] = cvt4(((const float4*)W_hh)[i4]);
    // W_ih -> bf16
    for (int i4 = tid0; i4 < NG_ * XK_ / 4; i4 += stride)
        ((v4bfv*)Wih_b)[i4] = cvt4(((const float4*)W_ih)[i4]);
    // Xin rows r = t*128+b : [emb[captions[b,t]], global_feats[b]]
    for (int i4 = tid0; i4 < T_ * B_ * XK_ / 4; i4 += stride) {
        int r = i4 / (XK_ / 4), c4 = i4 - r * (XK_ / 4);
        int c = c4 * 4;
        int t = r >> 7, b = r & 127;
        float4 v;
        if (c < E_) v = *(const float4*)&emb[(long)caps[b * T_ + t] * E_ + c];
        else        v = *(const float4*)&gfeat[(long)b * D_ + (c - E_)];
        ((v4bfv*)Xin_b)[i4] = cvt4(v);
    }
    // spatial -> bf16 (flattened [B*K, D])
    for (int i4 = tid0; i4 < B_ * KK_ * D_ / 4; i4 += stride)
        ((v4bfv*)Sp_b)[i4] = cvt4(((const float4*)spatial)[i4]);
    // Wv / Wg padded to 128 rows
    for (int i4 = tid0; i4 < NP_ * D_ / 4; i4 += stride) {
        int row = i4 >> 7;
        ((v4bfv*)Wv_b)[i4] = cvt4((row < KK_) ? ((const float4*)Wv)[i4] : z4);
        ((v4bfv*)Wg_b)[i4] = cvt4((row < KK_) ? ((const float4*)Wg)[i4] : z4);
    }
    // W_init_h / W_init_m
    for (int i4 = tid0; i4 < D_ * D_ / 4; i4 += stride) {
        ((v4bfv*)Winh_b)[i4] = cvt4(((const float4*)W_init_h)[i4]);
        ((v4bfv*)Winm_b)[i4] = cvt4(((const float4*)W_init_m)[i4]);
    }
    // global_feats -> bf16
    for (int i4 = tid0; i4 < B_ * D_ / 4; i4 += stride)
        ((v4bfv*)Gf_b)[i4] = cvt4(((const float4*)gfeat)[i4]);
    // combined gate bias
    for (int i = tid0; i < NG_; i += stride) bias_comb[i] = b_ih[i] + b_hh[i];
    // padded small biases
    for (int i = tid0; i < NP_; i += stride) {
        bv_pad[i] = (i < KK_) ? bv[i] : 0.f;
        bg_pad[i] = (i < KK_) ? bg[i] : 0.f;
    }
}

// ---------------------------------------------------------------------------
// Generic bf16 MFMA GEMM: C[M,N] = A[M,K] @ Bm[N,K]^T + bias[n]
// 128x128 tile, 4 waves, each wave 64x64 (4x4 of 16x16x32 MFMA).
// blockIdx.x = m-tile (fastest -> consecutive blocks share the B n-tile, L2
// locality), blockIdx.y = n-tile. Staging via global_load_lds width=16.
// OUTMODE: 0 = f32 store, 1 = bf16 store, 2 = logits (f32, clip n<n_real,
//          zero rows where t >= lengths[b], row m = b*T + t, stride out_stride)
// ---------------------------------------------------------------------------
template <int OUTMODE>
__global__ __launch_bounds__(256) void gemm_bt(
    const bf16* __restrict__ A, const bf16* __restrict__ Bm,
    const float* __restrict__ bias, void* __restrict__ Cout,
    int M, int N, int K, int out_stride, int n_real, const int* __restrict__ lengths)
{
    __shared__ bf16 As[128 * 32];
    __shared__ bf16 Bs[128 * 32];
    const int m0 = blockIdx.x * 128, n0 = blockIdx.y * 128;
    const int tid = threadIdx.x;
    const int w = tid >> 6, l = tid & 63;
    const int wm = (w >> 1) * 64, wn = (w & 1) * 64;
    const int lr = l & 15, lq = l >> 4;

    v4f acc[4][4] = {};

    for (int k0 = 0; k0 < K; k0 += 32) {
        __syncthreads();
        #pragma unroll
        for (int c = 0; c < 2; c++) {
            int u = c * 256 + tid;
            int row = u >> 2, kc = (u & 3) * 8;
            int u0 = c * 256 + (tid & ~63);   // wave-uniform LDS base
            GLOAD_LDS16(&A[(long)(m0 + row) * K + k0 + kc], &As[u0 * 8]);
            GLOAD_LDS16(&Bm[(long)(n0 + row) * K + k0 + kc], &Bs[u0 * 8]);
        }
        __syncthreads();
        v8bf af[4], bfv[4];
        #pragma unroll
        for (int s = 0; s < 4; s++) {
            af[s]  = *(const v8bf*)&As[(wm + s * 16 + lr) * 32 + lq * 8];
            bfv[s] = *(const v8bf*)&Bs[(wn + s * 16 + lr) * 32 + lq * 8];
        }
        #pragma unroll
        for (int i = 0; i < 4; i++)
            #pragma unroll
            for (int j = 0; j < 4; j++)
                acc[i][j] = __builtin_amdgcn_mfma_f32_16x16x32_bf16(af[i], bfv[j], acc[i][j], 0, 0, 0);
    }

    #pragma unroll
    for (int i = 0; i < 4; i++)
        #pragma unroll
        for (int j = 0; j < 4; j++)
            #pragma unroll
            for (int r = 0; r < 4; r++) {
                int m = m0 + wm + i * 16 + lq * 4 + r;
                int n = n0 + wn + j * 16 + lr;
                float v = acc[i][j][r];
                if (OUTMODE == 2) {
                    if (n < n_real) {
                        int t = m % T_, b = m / T_;
                        float o = (t < lengths[b]) ? (v + bias[n]) : 0.f;
                        ((float*)Cout)[(long)m * out_stride + n] = o;
                    }
                } else if (OUTMODE == 1) {
                    ((bf16*)Cout)[(long)m * out_stride + n] = (bf16)(v + bias[n]);
                } else {
                    ((float*)Cout)[(long)m * out_stride + n] = v + bias[n];
                }
            }
}

// ---------------------------------------------------------------------------
// Per-step fused kernel: gates = Xpre[t] + h_{t-1} @ W_hh^T, LSTM cell update.
// grid (8 b-tiles, 32 j-tiles) = 256 blocks (1/CU), 256 thr = 4 waves;
// wave w owns gate w, computes a 16(b) x 16(j) tile via a single MFMA chain.
// ---------------------------------------------------------------------------
__global__ __launch_bounds__(256) void step_kernel(
    const bf16* __restrict__ Hprev, bf16* __restrict__ Hnext,
    const bf16* __restrict__ Whh_b, const float* __restrict__ Xpre_t,
    float* __restrict__ mbuf, const int* __restrict__ lengths, int t)
{
    const int b0 = blockIdx.x * 16;
    const int j0 = blockIdx.y * 16;
    const int tid = threadIdx.x;
    const int w = tid >> 6, l = tid & 63;   // w = gate index (i,f,g,o)
    const int lr = l & 15, lq = l >> 4;
    __shared__ float g4[4][16][16];

    v4f acc = {};
    const bf16* Arow = Hprev + (long)(b0 + lr) * D_;
    const bf16* Brow = Whh_b + (long)(w * D_ + j0 + lr) * D_;

    #pragma unroll 4
    for (int kk = 0; kk < D_; kk += 32) {
        v8bf af  = *(const v8bf*)&Arow[kk + lq * 8];
        v8bf bfv = *(const v8bf*)&Brow[kk + lq * 8];
        acc = __builtin_amdgcn_mfma_f32_16x16x32_bf16(af, bfv, acc, 0, 0, 0);
    }
    #pragma unroll
    for (int r = 0; r < 4; r++)
        g4[w][lq * 4 + r][lr] = acc[r];
    __syncthreads();

    // pointwise: one of 16x16 elements per thread
    const int bi = tid >> 4, j = tid & 15;
    const int bgl = b0 + bi, jg = j0 + j;
    const float* xp = Xpre_t + (long)bgl * NG_ + jg;
    float gi = g4[0][bi][j] + xp[0];
    float gf = g4[1][bi][j] + xp[D_];
    float gc = g4[2][bi][j] + xp[2 * D_];
    float go = g4[3][bi][j] + xp[3 * D_];
    gi = 1.f / (1.f + expf(-gi));
    gf = 1.f / (1.f + expf(-gf));
    gc = tanhf(gc);
    go = 1.f / (1.f + expf(-go));
    long idx = (long)bgl * D_ + jg;
    float m_old = mbuf[idx];
    float h_old = (float)Hprev[idx];
    bool active = t < lengths[bgl];
    float m_new = gf * m_old + gi * gc;
    float h_new = go * tanhf(m_new);
    mbuf[idx] = active ? m_new : m_old;
    Hnext[idx] = (bf16)(active ? h_new : h_old);
}

// ---------------------------------------------------------------------------
// Attention + context. 4 waves/block; waves share b (spatial L1 reuse), each
// wave owns one t. z[k'] = sum_j wh[j]*tanh(Vproj[b,k',j] + g[j]) + bh;
// softmax over k'; c = alpha @ spatial[b]; ctx[b*T+t] = c + h_t (bf16).
// ---------------------------------------------------------------------------
__global__ __launch_bounds__(256) void attn_kernel(
    const bf16* __restrict__ Hb16, const float* __restrict__ g_all,
    const float* __restrict__ Vproj, const float* __restrict__ wh,
    const float* __restrict__ bh_att, const float* __restrict__ spatial,
    bf16* __restrict__ ctx)
{
    const int w = threadIdx.x >> 6, l = threadIdx.x & 63;
    const int b = blockIdx.x / 5, tg = blockIdx.x % 5;
    const int t = tg * 4 + w;
    const int r = t * 128 + b;            // row in g_all
    __shared__ float sg[4][64], sal[4][64], swh[64];

    if (w == 0) swh[l] = (l < KK_) ? wh[l] : 0.f;
    sg[w][l] = (l < KK_) ? g_all[(long)r * NP_ + l] : 0.f;
    __syncthreads();

    float z = -1e30f;
    if (l < KK_) {
        const float* vp = Vproj + (long)(b * KK_ + l) * NP_;
        float a = 0.f;
        for (int j = 0; j < KK_; j++)
            a += swh[j] * tanhf(vp[j] + sg[w][j]);
        z = a + bh_att[0];
    }
    float mx = z;
    #pragma unroll
    for (int o = 32; o > 0; o >>= 1) mx = fmaxf(mx, __shfl_xor(mx, o));
    float e = (l < KK_) ? expf(z - mx) : 0.f;
    float sm = e;
    #pragma unroll
    for (int o = 32; o > 0; o >>= 1) sm += __shfl_xor(sm, o);
    sal[w][l] = e / sm;
    __syncthreads();

    const bf16* hrow = Hb16 + (long)(t + 1) * B_ * D_ + (long)b * D_;
    const float* sp = spatial + (long)b * KK_ * D_;
    bf16* crow = ctx + (long)(b * T_ + t) * D_;
    for (int d = l; d < D_; d += 64) {
        float c = 0.f;
        for (int k = 0; k < KK_; k++)
            c += sal[w][k] * sp[k * D_ + d];
        crow[d] = (bf16)(c + (float)hrow[d]);
    }
}

// ---------------------------------------------------------------------------
extern "C" void kernel_launch(void* const* d_in, const int* in_sizes, int n_in,
                              void* d_out, int out_size, void* d_ws, size_t ws_size,
                              hipStream_t stream)
{
    const float* spatial  = (const float*)d_in[0];
    const float* gfeat    = (const float*)d_in[1];
    const int*   caps     = (const int*)d_in[2];
    const int*   lengths  = (const int*)d_in[3];
    const float* emb      = (const float*)d_in[4];
    const float* W_init_h = (const float*)d_in[5];
    const float* b_init_h = (const float*)d_in[6];
    const float* W_init_m = (const float*)d_in[7];
    const float* b_init_m = (const float*)d_in[8];
    const float* W_ih     = (const float*)d_in[9];
    const float* b_ih     = (const float*)d_in[10];
    const float* W_hh     = (const float*)d_in[11];
    const float* b_hh     = (const float*)d_in[12];
    const float* Wv       = (const float*)d_in[13];
    const float* bv       = (const float*)d_in[14];
    const float* Wg       = (const float*)d_in[15];
    const float* bg       = (const float*)d_in[16];
    const float* wh       = (const float*)d_in[17];
    const float* bh_att   = (const float*)d_in[18];
    const float* Wp       = (const float*)d_in[19];
    const float* bp       = (const float*)d_in[20];
    float* out = (float*)d_out;

    char* ws = (char*)d_ws;
    size_t off = 0;
    auto alloc = [&](size_t bytes) -> void* {
        off = (off + 255) & ~(size_t)255;
        void* p = ws + off;
        off += bytes;
        return p;
    };

    bf16* Wp_b   = (bf16*)alloc((size_t)VPAD * D_ * 2);
    bf16* Whh_b  = (bf16*)alloc((size_t)NG_ * D_ * 2);
    bf16* Wih_b  = (bf16*)alloc((size_t)NG_ * XK_ * 2);
    bf16* Xin_b  = (bf16*)alloc((size_t)T_ * B_ * XK_ * 2);
    bf16* Sp_b   = (bf16*)alloc((size_t)B_ * KK_ * D_ * 2);
    bf16* Wv_b   = (bf16*)alloc((size_t)NP_ * D_ * 2);
    bf16* Wg_b   = (bf16*)alloc((size_t)NP_ * D_ * 2);
    bf16* Winh_b = (bf16*)alloc((size_t)D_ * D_ * 2);
    bf16* Winm_b = (bf16*)alloc((size_t)D_ * D_ * 2);
    bf16* Gf_b   = (bf16*)alloc((size_t)B_ * D_ * 2);
    float* bias_comb = (float*)alloc(NG_ * 4);
    float* bv_pad    = (float*)alloc(NP_ * 4);
    float* bg_pad    = (float*)alloc(NP_ * 4);
    bf16* Hb16   = (bf16*)alloc((size_t)(T_ + 1) * B_ * D_ * 2);
    float* mbuf  = (float*)alloc((size_t)B_ * D_ * 4);
    float* Xpre  = (float*)alloc((size_t)T_ * B_ * NG_ * 4);
    float* VprojW = (float*)alloc((size_t)B_ * KK_ * NP_ * 4);
    float* g_allW = (float*)alloc((size_t)T_ * B_ * NP_ * 4);
    bf16* ctx    = (bf16*)alloc((size_t)T_ * B_ * D_ * 2);

    // 1. prep / conversions
    prep_kernel<<<1024, 256, 0, stream>>>(
        spatial, gfeat, caps, emb, W_init_h, W_init_m, W_ih, b_ih, W_hh, b_hh,
        Wv, bv, Wg, bg, Wp,
        Wp_b, Whh_b, Wih_b, Xin_b, Sp_b, Wv_b, Wg_b, Winh_b, Winm_b, Gf_b,
        bias_comb, bv_pad, bg_pad);

    // 2. h0 (bf16 into Hb16[0]) and m0 (f32 into mbuf)
    gemm_bt<1><<<dim3(1, 4), 256, 0, stream>>>(Gf_b, Winh_b, b_init_h, Hb16,
                                               B_, D_, D_, D_, 0, nullptr);
    gemm_bt<0><<<dim3(1, 4), 256, 0, stream>>>(Gf_b, Winm_b, b_init_m, mbuf,
                                               B_, D_, D_, D_, 0, nullptr);

    // 3. V_proj = spatial @ Wv^T + bv  -> [B*K, 128] f32
    gemm_bt<0><<<dim3((B_ * KK_) / 128, 1), 256, 0, stream>>>(
        Sp_b, Wv_b, bv_pad, VprojW, B_ * KK_, NP_, D_, NP_, 0, nullptr);

    // 4. Xpre = Xin @ W_ih^T + (b_ih + b_hh)  -> [T*B, 2048] f32
    gemm_bt<0><<<dim3((T_ * B_) / 128, NG_ / 128), 256, 0, stream>>>(
        Xin_b, Wih_b, bias_comb, Xpre, T_ * B_, NG_, XK_, NG_, 0, nullptr);

    // 5. sequential LSTM steps
    for (int t = 0; t < T_; t++) {
        step_kernel<<<dim3(8, 32), 256, 0, stream>>>(
            Hb16 + (size_t)t * B_ * D_, Hb16 + (size_t)(t + 1) * B_ * D_,
            Whh_b, Xpre + (size_t)t * B_ * NG_, mbuf, lengths, t);
    }

    // 6. g_all = H[1..T] @ Wg^T + bg  -> [T*B, 128] f32
    gemm_bt<0><<<dim3((T_ * B_) / 128, 1), 256, 0, stream>>>(
        Hb16 + (size_t)B_ * D_, Wg_b, bg_pad, g_allW, T_ * B_, NP_, D_, NP_, 0, nullptr);

    // 7. attention + ctx = c + h  (bf16, rows b*T+t)
    attn_kernel<<<B_ * 5, 256, 0, stream>>>(Hb16, g_allW, VprojW, wh, bh_att,
                                            spatial, ctx);

    // 8. logits = ctx @ Wp^T + bp, masked, -> d_out [B*T, V]
    gemm_bt<2><<<dim3((T_ * B_) / 128, VPAD / 128), 256, 0, stream>>>(
        ctx, Wp_b, bp, out, T_ * B_, VPAD, D_, V_, V_, lengths);
}